// Round 13
// baseline (270.224 us; speedup 1.0000x reference)
//
#include <hip/hip_runtime.h>
#include <hip/hip_bf16.h>
#include <cmath>

// Problem constants
#define B_   8
#define N_   4096
#define DIN1 64
#define DHID 128
#define DOUT2 64
#define MAXDEG 256

template <int SH>
__device__ __forceinline__ float dpp_shr_add(float p) {
    int t = __builtin_amdgcn_update_dpp(0, __float_as_int(p),
                                        0x110 | SH, 0xF, 0xF, true);
    return p + __int_as_float(t);
}
// Row-sum lands on the TOP lane of each GRPL-lane subgroup (row_shr moves
// values toward higher lanes). For GRPL=8 the shr 4/2/1 chain keeps each
// half-row's top lane (7,15,...) uncontaminated by the other half.
template <int GRPL>
__device__ __forceinline__ float dpp_reduce(float p) {
    if constexpr (GRPL == 16) p = dpp_shr_add<8>(p);
    p = dpp_shr_add<4>(p);
    p = dpp_shr_add<2>(p);
    p = dpp_shr_add<1>(p);
    return p;   // valid on lane GRPL-1 of each subgroup
}

// ---------------------------------------------------------------------------
// Kernel 1: adjacency -> neighbor lists. One WAVE per row; ballot+popc
// compaction (no LDS, no atomics, no barriers).
// ---------------------------------------------------------------------------
__global__ __launch_bounds__(256) void k_build_csr(
    const float* __restrict__ graph, int* __restrict__ cnt, int* __restrict__ idx)
{
    const int wave = threadIdx.x >> 6;
    const int lane = threadIdx.x & 63;
    const int n = blockIdx.x * 4 + wave;
    const unsigned long long below_mask = (1ULL << lane) - 1ULL;

    const float4* __restrict__ row4 = (const float4*)(graph + (size_t)n * N_);
    int* __restrict__ myidx = idx + (size_t)n * MAXDEG;

    int base = 0;
    for (int it = 0; it < N_ / 256; ++it) {      // 16 iterations
        const int i4 = it * 64 + lane;
        float4 g = row4[i4];
        const int e = 4 * i4;
#pragma unroll
        for (int c = 0; c < 4; ++c) {
            const float gc = (c == 0) ? g.x : (c == 1) ? g.y : (c == 2) ? g.z : g.w;
            const unsigned long long mk = __ballot(gc != 0.0f);
            const int pos = base + __popcll(mk & below_mask);
            if (gc != 0.0f && pos < MAXDEG) myidx[pos] = e + c;
            base += __popcll(mk);                // wave-uniform
        }
    }
    if (lane == 0) cnt[n] = (base < MAXDEG) ? base : MAXDEG;
}

// ---------------------------------------------------------------------------
// Kernel 2: register-tiled linear. out[r,k] = sum_d x[r,d]*W[k,d].
// ---------------------------------------------------------------------------
template <int DIN, int DOUT>
__global__ __launch_bounds__(256) void k_linear(
    const float* __restrict__ x, const float* __restrict__ W,
    float* __restrict__ out)
{
    constexpr int CG = DOUT / 4;
    constexpr int RG = 256 / CG;
    constexpr int TR = 32 / RG;

    __shared__ float sWt[DIN][DOUT + 4];

    const int t = threadIdx.x;
    const float4* W4 = (const float4*)W;
    for (int i = t; i < DOUT * (DIN / 4); i += 256) {
        int kk = i / (DIN / 4);
        int d4 = i % (DIN / 4);
        float4 w = W4[i];
        sWt[4 * d4 + 0][kk] = w.x;
        sWt[4 * d4 + 1][kk] = w.y;
        sWt[4 * d4 + 2][kk] = w.z;
        sWt[4 * d4 + 3][kk] = w.w;
    }
    __syncthreads();

    const int rg = t / CG;
    const int c  = t % CG;
    const int base = blockIdx.x * 32;
    const float4* x4 = (const float4*)x;

    float acc[TR][4];
#pragma unroll
    for (int i = 0; i < TR; ++i)
#pragma unroll
        for (int j = 0; j < 4; ++j) acc[i][j] = 0.0f;

    for (int d4 = 0; d4 < DIN / 4; ++d4) {
        float4 xf[TR];
#pragma unroll
        for (int i = 0; i < TR; ++i)
            xf[i] = x4[(size_t)(base + rg * TR + i) * (DIN / 4) + d4];
        float4 wf[4];
#pragma unroll
        for (int dd = 0; dd < 4; ++dd)
            wf[dd] = *(const float4*)&sWt[4 * d4 + dd][4 * c];
#pragma unroll
        for (int i = 0; i < TR; ++i) {
            acc[i][0] += xf[i].x * wf[0].x + xf[i].y * wf[1].x + xf[i].z * wf[2].x + xf[i].w * wf[3].x;
            acc[i][1] += xf[i].x * wf[0].y + xf[i].y * wf[1].y + xf[i].z * wf[2].y + xf[i].w * wf[3].y;
            acc[i][2] += xf[i].x * wf[0].z + xf[i].y * wf[1].z + xf[i].z * wf[2].z + xf[i].w * wf[3].z;
            acc[i][3] += xf[i].x * wf[0].w + xf[i].y * wf[1].w + xf[i].z * wf[2].w + xf[i].w * wf[3].w;
        }
    }

#pragma unroll
    for (int i = 0; i < TR; ++i) {
        float4 o = {acc[i][0], acc[i][1], acc[i][2], acc[i][3]};
        ((float4*)out)[(size_t)(base + rg * TR + i) * CG + c] = o;
    }
}

// ---------------------------------------------------------------------------
// Kernel 3: online-softmax sparse masked attention (round-11 shape, group
// size templated). One query per wave, one batch per wave (b = bid&7 keeps
// each XCD's L2 working set = one batch's h -- proven critical in R12).
// GRPL lanes per neighbor stream: 16 for D=128 (4 streams), 8 for D=64
// (8 streams -> half the iterations). DPP subgroup reduce (pure VALU),
// wave-uniform ballot skip-test on subgroup-top lanes; terms with
// p <= m-100 underflow exp to exactly 0 -> skipping is bit-neutral; taken
// path is the exact two-sided flash update. 32-bit byte offsets in LDS;
// 16 zero-offset pads -> guard-free depth-2 triple-buffer prefetch.
// Exact torch masked_fill(s==0) semantics; all-masked fallback rare path.
// ---------------------------------------------------------------------------
template <int D, bool RELU>
__global__ __launch_bounds__(256) void k_attn(
    const float* __restrict__ h, const int* __restrict__ cnt,
    const int* __restrict__ idx, const float* __restrict__ bias,
    float* __restrict__ out)
{
    constexpr int V    = D / 4;                  // float4s per row
    constexpr int GRPL = (D == 128) ? 16 : 8;    // lanes per stream
    constexpr int GS   = 64 / GRPL;              // streams per wave (4 or 8)
    constexpr int NF   = V / GRPL;               // float4s per lane (2)
    constexpr int RB   = D * 4;                  // row bytes
    const unsigned long long TOPMASK =
        (GRPL == 16) ? 0x8000800080008000ULL : 0x8080808080808080ULL;

    const int bid  = blockIdx.x;
    const int b    = bid & 7;                    // batch -> XCD pinning
    const int wave = threadIdx.x >> 6;
    const int lane = threadIdx.x & 63;
    const int n    = (bid >> 3) * 4 + wave;      // one query per wave
    const int grp  = lane / GRPL;
    const int gl   = lane % GRPL;
    const int gtop = lane | (GRPL - 1);          // subgroup TOP lane

    __shared__ int s_off[4][MAXDEG + 16];        // wave-private byte offsets

    const int k = cnt[n];
    const int* __restrict__ myidx = idx + (size_t)n * MAXDEG;
    for (int j = lane; j < k; j += 64) s_off[wave][j] = myidx[j] * RB;
    if (lane < 16) s_off[wave][k + lane] = 0;    // pad: safe prefetch targets

    const char* __restrict__ hb = (const char*)h + (size_t)b * N_ * RB;
    const int lb = gl * 16;                       // lane's byte slot in row

    float4 qf[NF];
#pragma unroll
    for (int i = 0; i < NF; ++i)
        qf[i] = *(const float4*)(hb + (size_t)n * RB + lb + GRPL * 16 * i);

    // self-score init: m = ||q||^2, broadcast from TOP lane (group-uniform)
    float m;
    {
        float p = 0.0f;
#pragma unroll
        for (int i = 0; i < NF; ++i)
            p += qf[i].x * qf[i].x + qf[i].y * qf[i].y
               + qf[i].z * qf[i].z + qf[i].w * qf[i].w;
        p = dpp_reduce<GRPL>(p);
        const float pb = __shfl(p, gtop, 64);
        m = (pb != 0.0f) ? pb : -INFINITY;
    }
    float mt = m - 100.0f;                       // skip threshold (uniform)
    float s = 0.0f;
    float4 acc[NF];
#pragma unroll
    for (int i = 0; i < NF; ++i) acc[i] = {0.0f, 0.0f, 0.0f, 0.0f};

    auto loadrow = [&](float4 (&r)[NF], int j) {
        const char* hm = hb + s_off[wave][j];
#pragma unroll
        for (int i = 0; i < NF; ++i)
            r[i] = *(const float4*)(hm + lb + GRPL * 16 * i);
    };
    auto process = [&](const float4 (&cur)[NF]) {
        float p = 0.0f;
#pragma unroll
        for (int i = 0; i < NF; ++i)
            p += qf[i].x * cur[i].x + qf[i].y * cur[i].y
               + qf[i].z * cur[i].z + qf[i].w * cur[i].w;
        p = dpp_reduce<GRPL>(p);                  // TOP lane holds true sum
        if (__builtin_expect((__ballot(p > mt) & TOPMASK) != 0ULL, 0)) {
            const float pb = __shfl(p, gtop, 64); // true subgroup sum
            const bool valid = (pb != 0.0f);      // dot==0 => masked (torch)
            const float pm   = valid ? pb : m;
            const float newm = fmaxf(m, pm);
            const float f = (m == newm) ? 1.0f : __expf(m - newm);
            const float e = valid ? __expf(pb - newm) : 0.0f;
            s = s * f + e;
#pragma unroll
            for (int i = 0; i < NF; ++i) {
                acc[i].x = acc[i].x * f + e * cur[i].x;
                acc[i].y = acc[i].y * f + e * cur[i].y;
                acc[i].z = acc[i].z * f + e * cur[i].z;
                acc[i].w = acc[i].w * f + e * cur[i].w;
            }
            m = newm;
            mt = m - 100.0f;
        }
    };

    // depth-2 guard-free triple-buffer pipeline (pads make overshoot safe)
    {
        float4 r0[NF], r1[NF], r2[NF];
        loadrow(r0, grp);
        loadrow(r1, grp + GS);
        int j = grp;
        while (j < k) {
            loadrow(r2, j + 2 * GS);
            process(r0);
            j += GS; if (j >= k) break;
            loadrow(r0, j + 2 * GS);
            process(r1);
            j += GS; if (j >= k) break;
            loadrow(r1, j + 2 * GS);
            process(r2);
            j += GS;
        }
    }

    // merge the GS subgroup states (xor GRPL..32); all 64 lanes converge
#pragma unroll
    for (int mask = GRPL; mask <= 32; mask <<= 1) {
        const float m2 = __shfl_xor(m, mask, 64);
        const float s2 = __shfl_xor(s, mask, 64);
        float4 a2[NF];
#pragma unroll
        for (int i = 0; i < NF; ++i) {
            a2[i].x = __shfl_xor(acc[i].x, mask, 64);
            a2[i].y = __shfl_xor(acc[i].y, mask, 64);
            a2[i].z = __shfl_xor(acc[i].z, mask, 64);
            a2[i].w = __shfl_xor(acc[i].w, mask, 64);
        }
        const float mm = fmaxf(m, m2);
        const float f1 = (m  == mm) ? 1.0f : __expf(m  - mm);  // -inf guard
        const float f2 = (m2 == mm) ? 1.0f : __expf(m2 - mm);
        s = s * f1 + s2 * f2;
#pragma unroll
        for (int i = 0; i < NF; ++i) {
            acc[i].x = acc[i].x * f1 + a2[i].x * f2;
            acc[i].y = acc[i].y * f1 + a2[i].y * f2;
            acc[i].z = acc[i].z * f1 + a2[i].z * f2;
            acc[i].w = acc[i].w * f1 + a2[i].w * f2;
        }
        m = mm;
    }

    if (s > 0.0f) {
        // normal epilogue: subgroup 0 writes the row
        if (grp == 0) {
            const float4* bias4 = (const float4*)bias;
            const float inv = 1.0f / s;
#pragma unroll
            for (int i = 0; i < NF; ++i) {
                const float4 bi = bias4[gl + GRPL * i];
                float4 o;
                o.x = acc[i].x * inv + bi.x;
                o.y = acc[i].y * inv + bi.y;
                o.z = acc[i].z * inv + bi.z;
                o.w = acc[i].w * inv + bi.w;
                if (RELU) {
                    o.x = fmaxf(o.x, 0.0f); o.y = fmaxf(o.y, 0.0f);
                    o.z = fmaxf(o.z, 0.0f); o.w = fmaxf(o.w, 0.0f);
                }
                ((float4*)out)[((size_t)b * N_ + n) * V + gl + GRPL * i] = o;
            }
        }
    } else {
        // RARE path (all scores masked): uniform softmax over all N rows ->
        // column mean of h[b]. Never taken unless the whole q row is zero.
        const float4* hb4 = (const float4*)hb;
        constexpr int RS = 64 / V;
        const int sl = lane % V;
        const int rs = lane / V;
        float4 a = {0.0f, 0.0f, 0.0f, 0.0f};
        for (int row = rs; row < N_; row += RS) {
            float4 v = hb4[(size_t)row * V + sl];
            a.x += v.x; a.y += v.y; a.z += v.z; a.w += v.w;
        }
#pragma unroll
        for (int mask = V; mask < 64; mask <<= 1) {
            a.x += __shfl_xor(a.x, mask, 64);
            a.y += __shfl_xor(a.y, mask, 64);
            a.z += __shfl_xor(a.z, mask, 64);
            a.w += __shfl_xor(a.w, mask, 64);
        }
        if (lane < V) {
            constexpr float invN = 1.0f / (float)N_;
            const float4 bi = ((const float4*)bias)[sl];
            float4 o;
            o.x = a.x * invN + bi.x;
            o.y = a.y * invN + bi.y;
            o.z = a.z * invN + bi.z;
            o.w = a.w * invN + bi.w;
            if (RELU) {
                o.x = fmaxf(o.x, 0.0f); o.y = fmaxf(o.y, 0.0f);
                o.z = fmaxf(o.z, 0.0f); o.w = fmaxf(o.w, 0.0f);
            }
            ((float4*)out)[((size_t)b * N_ + n) * V + sl] = o;
        }
    }
}

// ---------------------------------------------------------------------------
// Launch
// ---------------------------------------------------------------------------
extern "C" void kernel_launch(void* const* d_in, const int* in_sizes, int n_in,
                              void* d_out, int out_size, void* d_ws, size_t ws_size,
                              hipStream_t stream) {
    (void)in_sizes; (void)n_in; (void)out_size; (void)ws_size;

    const float* flow_x = (const float*)d_in[0];
    const float* graph  = (const float*)d_in[1];
    const float* W1     = (const float*)d_in[2];
    const float* b1     = (const float*)d_in[3];
    const float* W2     = (const float*)d_in[4];
    const float* b2     = (const float*)d_in[5];
    float* out = (float*)d_out;

    char* p = (char*)d_ws;
    auto carve = [&](size_t bytes) -> void* {
        void* r = (void*)p;
        p += (bytes + 255) & ~(size_t)255;
        return r;
    };
    int*   nbr_cnt = (int*)carve((size_t)N_ * sizeof(int));
    int*   nbr_idx = (int*)carve((size_t)N_ * MAXDEG * sizeof(int));
    float* h1      = (float*)carve((size_t)B_ * N_ * DHID * sizeof(float));
    float* x2      = (float*)carve((size_t)B_ * N_ * DHID * sizeof(float));
    float* h2      = (float*)carve((size_t)B_ * N_ * DOUT2 * sizeof(float));

    // 1. adjacency -> neighbor lists (wave-per-row ballot compaction)
    k_build_csr<<<N_ / 4, 256, 0, stream>>>(graph, nbr_cnt, nbr_idx);

    // 2. layer 1 linear
    k_linear<DIN1, DHID><<<(B_ * N_) / 32, 256, 0, stream>>>(flow_x, W1, h1);

    // 3. layer 1 attention + bias + relu (one query per wave, 16-lane grps)
    k_attn<DHID, true><<<N_ * B_ / 4, 256, 0, stream>>>(h1, nbr_cnt, nbr_idx, b1, x2);

    // 4. layer 2 linear
    k_linear<DHID, DOUT2><<<(B_ * N_) / 32, 256, 0, stream>>>(x2, W2, h2);

    // 5. layer 2 attention + bias -> d_out (8-lane grps: 8 streams/wave)
    k_attn<DOUT2, false><<<N_ * B_ / 4, 256, 0, stream>>>(h2, nbr_cnt, nbr_idx, b2, out);
}